// Round 3
// baseline (454.740 us; speedup 1.0000x reference)
//
#include <hip/hip_runtime.h>
#include <math.h>

#define N_NODES 50000
#define N_EDGES 800000
#define FDIM 128
#define NH 8
#define NC 32
#define D1 256      // NH*NC
#define NCLS 16
#define NGRP 64
#define NEG 0.2f
#define E_TOT (N_EDGES + N_NODES)

typedef __attribute__((ext_vector_type(8))) unsigned short u16x8;
typedef __attribute__((ext_vector_type(8))) short short8;
typedef __attribute__((ext_vector_type(4))) float f32x4;

static __device__ __forceinline__ float bf2f(unsigned short u) {
    return __uint_as_float(((unsigned int)u) << 16);
}
static __device__ __forceinline__ unsigned short f2bf(float f) {
    unsigned int b = __float_as_uint(f);
    return (unsigned short)((b + 0x7FFFu + ((b >> 16) & 1u)) >> 16);
}

// ------ init: cnt=1, pool accums=0, W1 -> bf16 transposed+swizzled w1t --------
// w1t layout: [n][k] bf16 with k-index XOR-swizzled by ((n&7)<<3) so that
// gemm1 can stage it LINEARLY into LDS and read bank-conflict-free b128 frags.
__global__ void k_init(const float* __restrict__ W1, unsigned short* __restrict__ w1t,
                       int* __restrict__ cnt, float* __restrict__ poolS,
                       int* __restrict__ poolCnt) {
    int i = blockIdx.x * 256 + threadIdx.x;
    if (i < N_NODES) cnt[i] = 1;               // self loop
    if (i < NGRP * NCLS) poolS[i] = 0.f;
    if (i < NGRP) poolCnt[i] = 0;
    if (i < FDIM * D1) {
        int n = i & 255, k = i >> 8;           // W1[k][n], coalesced read
        w1t[n * FDIM + (k ^ ((n & 7) << 3))] = f2bf(W1[i]);
    }
}

// ------ GEMM1 via MFMA bf16: xp1b[N,256] = bf16(x) @ bf16(W1), fused al1 ------
// block: 256 thr = 4 waves, 64 rows; wave (wr,wc): rows wr*32..+32, cols wc*128..+128
__global__ __launch_bounds__(256) void k_gemm1m(
    const float* __restrict__ x, const unsigned short* __restrict__ w1t,
    const float* __restrict__ a1s, const float* __restrict__ a1d,
    unsigned short* __restrict__ xp1b, float* __restrict__ al1s,
    float* __restrict__ al1d) {
    __shared__ unsigned short Bl[FDIM * D1];   // 64 KB, pre-swizzled [n][k] bf16
    for (int it = threadIdx.x; it < (FDIM * D1) / 8; it += 256)
        *(short8*)&Bl[it * 8] = *(const short8*)&w1t[it * 8];
    __syncthreads();

    const int l = threadIdx.x & 63;
    const int wid = threadIdx.x >> 6;
    const int wr = wid >> 1, wc = wid & 1;
    const int l15 = l & 15, l4 = l >> 4;
    const int base = blockIdx.x * 64;
    const int r0 = base + wr * 32;

    f32x4 acc[2][8] = {};
#pragma unroll
    for (int ks = 0; ks < 4; ++ks) {
        const int kk = ks * 32 + l4 * 8;
        short8 af[2];
#pragma unroll
        for (int rt = 0; rt < 2; ++rt) {
            int row = r0 + rt * 16 + l15;
            float4 v0 = make_float4(0.f, 0.f, 0.f, 0.f), v1 = v0;
            if (row < N_NODES) {
                const float* xr = x + (size_t)row * FDIM + kk;
                v0 = *(const float4*)xr;
                v1 = *(const float4*)(xr + 4);
            }
            short8 a;
            a[0] = (short)f2bf(v0.x); a[1] = (short)f2bf(v0.y);
            a[2] = (short)f2bf(v0.z); a[3] = (short)f2bf(v0.w);
            a[4] = (short)f2bf(v1.x); a[5] = (short)f2bf(v1.y);
            a[6] = (short)f2bf(v1.z); a[7] = (short)f2bf(v1.w);
            af[rt] = a;
        }
#pragma unroll
        for (int nt = 0; nt < 8; ++nt) {
            int col = wc * 128 + nt * 16 + l15;
            int bidx = col * FDIM + (kk ^ ((col & 7) << 3));
            short8 bf_ = *(const short8*)&Bl[bidx];
            acc[0][nt] = __builtin_amdgcn_mfma_f32_16x16x32_bf16(af[0], bf_, acc[0][nt], 0, 0, 0);
            acc[1][nt] = __builtin_amdgcn_mfma_f32_16x16x32_bf16(af[1], bf_, acc[1][nt], 0, 0, 0);
        }
    }
    // epilogue 1: bf16 stores (C/D: col=lane&15, row=(lane>>4)*4+reg)
#pragma unroll
    for (int rt = 0; rt < 2; ++rt) {
        int rbase = r0 + rt * 16 + l4 * 4;
#pragma unroll
        for (int nt = 0; nt < 8; ++nt) {
            int col = wc * 128 + nt * 16 + l15;
            f32x4 c = acc[rt][nt];
#pragma unroll
            for (int r = 0; r < 4; ++r) {
                int row = rbase + r;
                if (row < N_NODES) xp1b[(size_t)row * D1 + col] = f2bf(c[r]);
            }
        }
    }
    // epilogue 2: fused al1s/al1d (per-head dot over 32 cols + 16-lane reduce)
#pragma unroll
    for (int hl = 0; hl < 4; ++hl) {
        int hg = wc * 4 + hl;
        float as0 = a1s[hg * NC + l15], as1 = a1s[hg * NC + 16 + l15];
        float ad0 = a1d[hg * NC + l15], ad1 = a1d[hg * NC + 16 + l15];
#pragma unroll
        for (int rt = 0; rt < 2; ++rt) {
            f32x4 c0 = acc[rt][2 * hl], c1 = acc[rt][2 * hl + 1];
#pragma unroll
            for (int r = 0; r < 4; ++r) {
                float ss = c0[r] * as0 + c1[r] * as1;
                float dd = c0[r] * ad0 + c1[r] * ad1;
#pragma unroll
                for (int msk = 1; msk < 16; msk <<= 1) {
                    ss += __shfl_xor(ss, msk);
                    dd += __shfl_xor(dd, msk);
                }
                int row = r0 + rt * 16 + l4 * 4 + r;
                if (l15 == 0 && row < N_NODES) {
                    al1s[row * NH + hg] = ss;
                    al1d[row * NH + hg] = dd;
                }
            }
        }
    }
}

// ---------------- CSR build + batch histogram ---------------------------------
__global__ void k_hist(const int* __restrict__ ei, const int* __restrict__ batch,
                       int* __restrict__ cnt, int* __restrict__ poolCnt) {
    int e = blockIdx.x * blockDim.x + threadIdx.x;
    if (e < N_NODES) atomicAdd(&poolCnt[batch[e]], 1);
    if (e >= N_EDGES) return;
    atomicAdd(&cnt[ei[N_EDGES + e]], 1);
}

__global__ void k_scan1(const int* __restrict__ cnt, int* __restrict__ rowptr,
                        int* __restrict__ bsums) {
    __shared__ int sh[256];
    int i = blockIdx.x * 256 + threadIdx.x;
    int v = (i < N_NODES) ? cnt[i] : 0;
    sh[threadIdx.x] = v;
    __syncthreads();
    for (int d = 1; d < 256; d <<= 1) {
        int t = (threadIdx.x >= d) ? sh[threadIdx.x - d] : 0;
        __syncthreads();
        sh[threadIdx.x] += t;
        __syncthreads();
    }
    if (i < N_NODES) rowptr[i] = sh[threadIdx.x] - v;   // exclusive
    if (threadIdx.x == 255) bsums[blockIdx.x] = sh[255];
}

__global__ void k_scan2(int* __restrict__ bsums, int nb) {
    __shared__ int sh[256];
    int v = (threadIdx.x < nb) ? bsums[threadIdx.x] : 0;
    sh[threadIdx.x] = v;
    __syncthreads();
    for (int d = 1; d < 256; d <<= 1) {
        int t = (threadIdx.x >= d) ? sh[threadIdx.x - d] : 0;
        __syncthreads();
        sh[threadIdx.x] += t;
        __syncthreads();
    }
    bsums[threadIdx.x] = sh[threadIdx.x] - v;           // exclusive
}

__global__ void k_scan3(int* __restrict__ rowptr, const int* __restrict__ bsums,
                        int* __restrict__ cursor) {
    int i = blockIdx.x * 256 + threadIdx.x;
    if (i < N_NODES) {
        int r = rowptr[i] + bsums[blockIdx.x];
        rowptr[i] = r;
        cursor[i] = r;
    }
}

__global__ void k_scatter(const int* __restrict__ ei, int* __restrict__ cursor,
                          int* __restrict__ esrc) {
    int e = blockIdx.x * blockDim.x + threadIdx.x;
    if (e >= E_TOT) return;
    int s, d;
    if (e < N_EDGES) { s = ei[e]; d = ei[N_EDGES + e]; }
    else { s = d = e - N_EDGES; }
    int pos = atomicAdd(&cursor[d], 1);
    esrc[pos] = s;
}

// ---------------- attention layer 1 (wave per dst node) -----------------------
__global__ __launch_bounds__(256) void k_att1(
    const unsigned short* __restrict__ xp1b, const float* __restrict__ al1s,
    const float* __restrict__ al1d, const float* __restrict__ b1,
    const int* __restrict__ rowptr, const int* __restrict__ cnt,
    const int* __restrict__ esrc, unsigned short* __restrict__ h1b) {
    __shared__ int s_src[4][64];
    __shared__ float s_alpha[4][64 * 8];
    int wv = threadIdx.x >> 6;
    int lane = threadIdx.x & 63;
    int n = blockIdx.x * 4 + wv;          // grid exactly covers 50000 = 12500*4
    int start = rowptr[n];
    int deg = cnt[n];
    int dcap = deg < 64 ? deg : 64;
    for (int j = lane; j < dcap; j += 64) s_src[wv][j] = esrc[start + j];
    // pass 1: online softmax stats, 8 edges x 8 heads
    int h = lane & 7, eg = lane >> 3;
    float ald = al1d[n * NH + h];
    float m = -1e30f, den = 0.f;
    for (int j = eg; j < dcap; j += 8) {
        int s = s_src[wv][j];
        float v = al1s[s * NH + h] + ald;
        v = v > 0.f ? v : NEG * v;
        if (v > m) { den = den * __expf(m - v) + 1.f; m = v; }
        else den += __expf(v - m);
    }
    for (int j = 64 + eg; j < deg; j += 8) {      // rare tail
        int s = esrc[start + j];
        float v = al1s[s * NH + h] + ald;
        v = v > 0.f ? v : NEG * v;
        if (v > m) { den = den * __expf(m - v) + 1.f; m = v; }
        else den += __expf(v - m);
    }
    for (int msk = 8; msk < 64; msk <<= 1) {
        float mo = __shfl_xor(m, msk), dn = __shfl_xor(den, msk);
        float nm = fmaxf(m, mo);
        den = den * __expf(m - nm) + dn * __expf(mo - nm);
        m = nm;
    }
    float rden1 = 1.f / den;
    // pass 1.5: alphas into LDS (lane-contiguous writes, conflict-free)
    for (int j = eg; j < dcap; j += 8) {
        int s = s_src[wv][j];
        float v = al1s[s * NH + h] + ald;
        v = v > 0.f ? v : NEG * v;
        s_alpha[wv][j * 8 + h] = __expf(v - m) * rden1;
    }
    // pass 2: pure alpha*gather-fma, 4 gathers in flight per half-wave
    int eh = lane >> 5;
    int l5 = lane & 31;
    int h2 = l5 >> 2;
    float m2 = __shfl(m, h2);
    float rd2 = __shfl(rden1, h2);
    float ald2 = al1d[n * NH + h2];
    const int cb = l5 << 3;
    float acc[8] = {0.f, 0.f, 0.f, 0.f, 0.f, 0.f, 0.f, 0.f};
    for (int j0 = 0; j0 < dcap; j0 += 8) {
        const unsigned short* p[4];
        float a[4];
#pragma unroll
        for (int k = 0; k < 4; ++k) {
            int e = j0 + eh + 2 * k;
            bool act = e < dcap;
            int ee = act ? e : 0;
            int s = s_src[wv][ee];
            a[k] = act ? s_alpha[wv][ee * 8 + h2] : 0.f;
            p[k] = xp1b + (size_t)s * D1 + cb;
        }
#pragma unroll
        for (int k = 0; k < 4; ++k) {
            u16x8 xv = *(const u16x8*)p[k];
#pragma unroll
            for (int c = 0; c < 8; ++c) acc[c] = fmaf(a[k], bf2f(xv[c]), acc[c]);
        }
    }
    for (int j = 64 + eh; j < deg; j += 2) {      // rare tail
        int s = esrc[start + j];
        float v = al1s[s * NH + h2] + ald2;
        v = v > 0.f ? v : NEG * v;
        float al = __expf(v - m2) * rd2;
        u16x8 xv = *(const u16x8*)(xp1b + (size_t)s * D1 + cb);
#pragma unroll
        for (int c = 0; c < 8; ++c) acc[c] = fmaf(al, bf2f(xv[c]), acc[c]);
    }
#pragma unroll
    for (int c = 0; c < 8; ++c) acc[c] += __shfl_xor(acc[c], 32);
    if (eh == 0) {
        u16x8 pk;
#pragma unroll
        for (int c = 0; c < 8; ++c) {
            float av = acc[c] + b1[cb + c];
            av = av > 0.f ? av : expm1f(av);   // ELU fused
            pk[c] = f2bf(av);
        }
        *(u16x8*)(h1b + (size_t)n * D1 + cb) = pk;
    }
}

// ---------------- GEMM2 (bf16 h1 in) + al2 epilogue ---------------------------
__global__ __launch_bounds__(256) void k_gemm2(
    const unsigned short* __restrict__ h1b, const float* __restrict__ W2,
    const float* __restrict__ a2s, const float* __restrict__ a2d,
    float* __restrict__ xp2, float* __restrict__ al2s, float* __restrict__ al2d) {
    __shared__ float w2s[D1 * NCLS];
    for (int i = threadIdx.x; i < D1 * NCLS; i += 256) w2s[i] = W2[i];
    __syncthreads();
    int n = blockIdx.x * 256 + threadIdx.x;
    if (n >= N_NODES) return;
    float4 acc[4];
#pragma unroll
    for (int q = 0; q < 4; ++q) acc[q] = make_float4(0.f, 0.f, 0.f, 0.f);
    const unsigned short* hr = h1b + (size_t)n * D1;
    for (int k0 = 0; k0 < D1; k0 += 8) {
        u16x8 hv = *(const u16x8*)(hr + k0);
#pragma unroll
        for (int j = 0; j < 8; ++j) {
            float hx = bf2f(hv[j]);
#pragma unroll
            for (int q = 0; q < 4; ++q) {
                float4 w = *(const float4*)(&w2s[(k0 + j) * NCLS + q * 4]);
                acc[q].x = fmaf(hx, w.x, acc[q].x);
                acc[q].y = fmaf(hx, w.y, acc[q].y);
                acc[q].z = fmaf(hx, w.z, acc[q].z);
                acc[q].w = fmaf(hx, w.w, acc[q].w);
            }
        }
    }
    float ss = 0.f, dd = 0.f;
#pragma unroll
    for (int q = 0; q < 4; ++q) {
        *(float4*)(xp2 + (size_t)n * NCLS + q * 4) = acc[q];
        float4 s4 = *(const float4*)(a2s + q * 4);
        float4 d4 = *(const float4*)(a2d + q * 4);
        ss += acc[q].x * s4.x + acc[q].y * s4.y + acc[q].z * s4.z + acc[q].w * s4.w;
        dd += acc[q].x * d4.x + acc[q].y * d4.y + acc[q].z * d4.z + acc[q].w * d4.w;
    }
    al2s[n] = ss;
    al2d[n] = dd;
}

// ------- attention layer 2 (wave per dst node) + fused mean-pool atomics ------
__global__ __launch_bounds__(256) void k_att2(
    const float* __restrict__ xp2, const float* __restrict__ al2s,
    const float* __restrict__ al2d, const int* __restrict__ batch,
    const int* __restrict__ rowptr, const int* __restrict__ cnt,
    const int* __restrict__ esrc, float* __restrict__ poolS) {
    int wave = threadIdx.x >> 6;
    int lane = threadIdx.x & 63;
    int n = blockIdx.x * 4 + wave;
    int start = rowptr[n];
    int deg = cnt[n];
    float ald = al2d[n];
    float m = -1e30f, den = 0.f;
    for (int j = lane; j < deg; j += 64) {
        float v = al2s[esrc[start + j]] + ald;
        v = v > 0.f ? v : NEG * v;
        if (v > m) { den = den * __expf(m - v) + 1.f; m = v; }
        else den += __expf(v - m);
    }
    for (int msk = 1; msk < 64; msk <<= 1) {
        float mo = __shfl_xor(m, msk), dn = __shfl_xor(den, msk);
        float nm = fmaxf(m, mo);
        den = den * __expf(m - nm) + dn * __expf(mo - nm);
        m = nm;
    }
    float rden = 1.f / den;
    int c = lane & 15;
    int eg = lane >> 4;                   // 4 edges x 16 channels
    float acc = 0.f;
    for (int j = eg; j < deg; j += 4) {
        int s = esrc[start + j];
        float v = al2s[s] + ald;
        v = v > 0.f ? v : NEG * v;
        acc += __expf(v - m) * rden * xp2[(size_t)s * NCLS + c];
    }
    acc += __shfl_xor(acc, 16);
    acc += __shfl_xor(acc, 32);
    if (lane < 16) {
        int g = batch[n];
        atomicAdd(&poolS[g * NCLS + lane], acc);
    }
}

__global__ void k_final(const float* __restrict__ poolS,
                        const int* __restrict__ poolCnt,
                        const float* __restrict__ b2, float* __restrict__ out) {
    int g = threadIdx.x;
    if (g >= NGRP) return;
    float inv = 1.f / fmaxf((float)poolCnt[g], 1.f);
    float v[NCLS];
    float m = -1e30f;
#pragma unroll
    for (int c = 0; c < NCLS; ++c) {
        v[c] = poolS[g * NCLS + c] * inv + b2[c];
        m = fmaxf(m, v[c]);
    }
    float s = 0.f;
#pragma unroll
    for (int c = 0; c < NCLS; ++c) s += expf(v[c] - m);
    float lse = m + logf(s);
#pragma unroll
    for (int c = 0; c < NCLS; ++c) out[g * NCLS + c] = v[c] - lse;
}

extern "C" void kernel_launch(void* const* d_in, const int* in_sizes, int n_in,
                              void* d_out, int out_size, void* d_ws, size_t ws_size,
                              hipStream_t stream) {
    const float* x    = (const float*)d_in[0];
    const int*   ei   = (const int*)d_in[1];
    const int*   batch = (const int*)d_in[2];
    const float* W1   = (const float*)d_in[3];
    const float* a1s  = (const float*)d_in[4];
    const float* a1d  = (const float*)d_in[5];
    const float* b1   = (const float*)d_in[6];
    const float* W2   = (const float*)d_in[7];
    const float* a2s  = (const float*)d_in[8];
    const float* a2d  = (const float*)d_in[9];
    const float* b2   = (const float*)d_in[10];
    float* out = (float*)d_out;

    float* f = (float*)d_ws;
    float* al1s_ = f;  f += (size_t)N_NODES * NH;
    float* al1d_ = f;  f += (size_t)N_NODES * NH;
    float* xp2   = f;  f += (size_t)N_NODES * NCLS;
    float* al2s_ = f;  f += N_NODES;
    float* al2d_ = f;  f += N_NODES;
    float* poolS = f;  f += NGRP * NCLS;
    unsigned short* xp1b = (unsigned short*)f;
    unsigned short* h1b  = xp1b + (size_t)N_NODES * D1;
    unsigned short* w1t  = h1b + (size_t)N_NODES * D1;
    int* cnt    = (int*)(w1t + FDIM * D1);
    int* rowptr = cnt + N_NODES;
    int* cursor = rowptr + N_NODES;
    int* esrc   = cursor + N_NODES;
    int* bsums  = esrc + E_TOT;
    int* poolCnt = bsums + 256;

    const int NB_N = (N_NODES + 255) / 256;   // 196

    k_init<<<NB_N, 256, 0, stream>>>(W1, w1t, cnt, poolS, poolCnt);
    k_gemm1m<<<(N_NODES + 63) / 64, 256, 0, stream>>>(x, w1t, a1s, a1d, xp1b, al1s_, al1d_);
    k_hist<<<(N_EDGES + 255) / 256, 256, 0, stream>>>(ei, batch, cnt, poolCnt);
    k_scan1<<<NB_N, 256, 0, stream>>>(cnt, rowptr, bsums);
    k_scan2<<<1, 256, 0, stream>>>(bsums, NB_N);
    k_scan3<<<NB_N, 256, 0, stream>>>(rowptr, bsums, cursor);
    k_scatter<<<(E_TOT + 255) / 256, 256, 0, stream>>>(ei, cursor, esrc);
    k_att1<<<N_NODES / 4, 256, 0, stream>>>(xp1b, al1s_, al1d_, b1, rowptr, cnt, esrc, h1b);
    k_gemm2<<<NB_N, 256, 0, stream>>>(h1b, W2, a2s, a2d, xp2, al2s_, al2d_);
    k_att2<<<N_NODES / 4, 256, 0, stream>>>(xp2, al2s_, al2d_, batch, rowptr, cnt, esrc, poolS);
    k_final<<<1, 64, 0, stream>>>(poolS, poolCnt, b2, out);
}

// Round 4
// 280.508 us; speedup vs baseline: 1.6211x; 1.6211x over previous
//
#include <hip/hip_runtime.h>
#include <math.h>

#define N_NODES 50000
#define N_EDGES 800000
#define FDIM 128
#define NH 8
#define NC 32
#define D1 256      // NH*NC
#define NCLS 16
#define NGRP 64
#define NEG 0.2f
#define E_TOT (N_EDGES + N_NODES)

typedef __attribute__((ext_vector_type(8))) unsigned short u16x8;
typedef __attribute__((ext_vector_type(8))) short short8;
typedef __attribute__((ext_vector_type(4))) float f32x4;

static __device__ __forceinline__ float bf2f(unsigned short u) {
    return __uint_as_float(((unsigned int)u) << 16);
}
static __device__ __forceinline__ unsigned short f2bf(float f) {
    unsigned int b = __float_as_uint(f);
    return (unsigned short)((b + 0x7FFFu + ((b >> 16) & 1u)) >> 16);
}

// ------ init: cnt=1, pool accums=0, W1 -> bf16 transposed+swizzled w1t --------
__global__ void k_init(const float* __restrict__ W1, unsigned short* __restrict__ w1t,
                       int* __restrict__ cnt, float* __restrict__ poolS,
                       float* __restrict__ poolC) {
    int i = blockIdx.x * 256 + threadIdx.x;
    if (i < N_NODES) cnt[i] = 1;               // self loop
    if (i < NGRP * NCLS) poolS[i] = 0.f;
    if (i < NGRP) poolC[i] = 0.f;
    if (i < FDIM * D1) {
        int n = i & 255, k = i >> 8;           // W1[k][n], coalesced read
        w1t[n * FDIM + (k ^ ((n & 7) << 3))] = f2bf(W1[i]);
    }
}

// ------ GEMM1 via MFMA bf16: xp1b[N,256] = bf16(x) @ bf16(W1), fused al1 ------
__global__ __launch_bounds__(256) void k_gemm1m(
    const float* __restrict__ x, const unsigned short* __restrict__ w1t,
    const float* __restrict__ a1s, const float* __restrict__ a1d,
    unsigned short* __restrict__ xp1b, float* __restrict__ al1s,
    float* __restrict__ al1d) {
    __shared__ unsigned short Bl[FDIM * D1];   // 64 KB, pre-swizzled [n][k] bf16
    for (int it = threadIdx.x; it < (FDIM * D1) / 8; it += 256)
        *(short8*)&Bl[it * 8] = *(const short8*)&w1t[it * 8];
    __syncthreads();

    const int l = threadIdx.x & 63;
    const int wid = threadIdx.x >> 6;
    const int wr = wid >> 1, wc = wid & 1;
    const int l15 = l & 15, l4 = l >> 4;
    const int base = blockIdx.x * 64;
    const int r0 = base + wr * 32;

    f32x4 acc[2][8] = {};
#pragma unroll
    for (int ks = 0; ks < 4; ++ks) {
        const int kk = ks * 32 + l4 * 8;
        short8 af[2];
#pragma unroll
        for (int rt = 0; rt < 2; ++rt) {
            int row = r0 + rt * 16 + l15;
            float4 v0 = make_float4(0.f, 0.f, 0.f, 0.f), v1 = v0;
            if (row < N_NODES) {
                const float* xr = x + (size_t)row * FDIM + kk;
                v0 = *(const float4*)xr;
                v1 = *(const float4*)(xr + 4);
            }
            short8 a;
            a[0] = (short)f2bf(v0.x); a[1] = (short)f2bf(v0.y);
            a[2] = (short)f2bf(v0.z); a[3] = (short)f2bf(v0.w);
            a[4] = (short)f2bf(v1.x); a[5] = (short)f2bf(v1.y);
            a[6] = (short)f2bf(v1.z); a[7] = (short)f2bf(v1.w);
            af[rt] = a;
        }
#pragma unroll
        for (int nt = 0; nt < 8; ++nt) {
            int col = wc * 128 + nt * 16 + l15;
            int bidx = col * FDIM + (kk ^ ((col & 7) << 3));
            short8 bf_ = *(const short8*)&Bl[bidx];
            acc[0][nt] = __builtin_amdgcn_mfma_f32_16x16x32_bf16(af[0], bf_, acc[0][nt], 0, 0, 0);
            acc[1][nt] = __builtin_amdgcn_mfma_f32_16x16x32_bf16(af[1], bf_, acc[1][nt], 0, 0, 0);
        }
    }
    // epilogue 1: bf16 stores (C/D: col=lane&15, row=(lane>>4)*4+reg)
#pragma unroll
    for (int rt = 0; rt < 2; ++rt) {
        int rbase = r0 + rt * 16 + l4 * 4;
#pragma unroll
        for (int nt = 0; nt < 8; ++nt) {
            int col = wc * 128 + nt * 16 + l15;
            f32x4 c = acc[rt][nt];
#pragma unroll
            for (int r = 0; r < 4; ++r) {
                int row = rbase + r;
                if (row < N_NODES) xp1b[(size_t)row * D1 + col] = f2bf(c[r]);
            }
        }
    }
    // epilogue 2: fused al1s/al1d
#pragma unroll
    for (int hl = 0; hl < 4; ++hl) {
        int hg = wc * 4 + hl;
        float as0 = a1s[hg * NC + l15], as1 = a1s[hg * NC + 16 + l15];
        float ad0 = a1d[hg * NC + l15], ad1 = a1d[hg * NC + 16 + l15];
#pragma unroll
        for (int rt = 0; rt < 2; ++rt) {
            f32x4 c0 = acc[rt][2 * hl], c1 = acc[rt][2 * hl + 1];
#pragma unroll
            for (int r = 0; r < 4; ++r) {
                float ss = c0[r] * as0 + c1[r] * as1;
                float dd = c0[r] * ad0 + c1[r] * ad1;
#pragma unroll
                for (int msk = 1; msk < 16; msk <<= 1) {
                    ss += __shfl_xor(ss, msk);
                    dd += __shfl_xor(dd, msk);
                }
                int row = r0 + rt * 16 + l4 * 4 + r;
                if (l15 == 0 && row < N_NODES) {
                    al1s[row * NH + hg] = ss;
                    al1d[row * NH + hg] = dd;
                }
            }
        }
    }
}

// ---------------- CSR build (edge histogram only) -----------------------------
__global__ void k_hist(const int* __restrict__ ei, int* __restrict__ cnt) {
    int e = blockIdx.x * blockDim.x + threadIdx.x;
    if (e >= N_EDGES) return;
    atomicAdd(&cnt[ei[N_EDGES + e]], 1);
}

__global__ void k_scan1(const int* __restrict__ cnt, int* __restrict__ rowptr,
                        int* __restrict__ bsums) {
    __shared__ int sh[256];
    int i = blockIdx.x * 256 + threadIdx.x;
    int v = (i < N_NODES) ? cnt[i] : 0;
    sh[threadIdx.x] = v;
    __syncthreads();
    for (int d = 1; d < 256; d <<= 1) {
        int t = (threadIdx.x >= d) ? sh[threadIdx.x - d] : 0;
        __syncthreads();
        sh[threadIdx.x] += t;
        __syncthreads();
    }
    if (i < N_NODES) rowptr[i] = sh[threadIdx.x] - v;   // exclusive
    if (threadIdx.x == 255) bsums[blockIdx.x] = sh[255];
}

__global__ void k_scan2(int* __restrict__ bsums, int nb) {
    __shared__ int sh[256];
    int v = (threadIdx.x < nb) ? bsums[threadIdx.x] : 0;
    sh[threadIdx.x] = v;
    __syncthreads();
    for (int d = 1; d < 256; d <<= 1) {
        int t = (threadIdx.x >= d) ? sh[threadIdx.x - d] : 0;
        __syncthreads();
        sh[threadIdx.x] += t;
        __syncthreads();
    }
    bsums[threadIdx.x] = sh[threadIdx.x] - v;           // exclusive
}

__global__ void k_scan3(int* __restrict__ rowptr, const int* __restrict__ bsums,
                        int* __restrict__ cursor) {
    int i = blockIdx.x * 256 + threadIdx.x;
    if (i < N_NODES) {
        int r = rowptr[i] + bsums[blockIdx.x];
        rowptr[i] = r;
        cursor[i] = r;
    }
}

__global__ void k_scatter(const int* __restrict__ ei, int* __restrict__ cursor,
                          int* __restrict__ esrc) {
    int e = blockIdx.x * blockDim.x + threadIdx.x;
    if (e >= E_TOT) return;
    int s, d;
    if (e < N_EDGES) { s = ei[e]; d = ei[N_EDGES + e]; }
    else { s = d = e - N_EDGES; }
    int pos = atomicAdd(&cursor[d], 1);
    esrc[pos] = s;
}

// ---------------- attention layer 1 (wave per dst node) -----------------------
__global__ __launch_bounds__(256) void k_att1(
    const unsigned short* __restrict__ xp1b, const float* __restrict__ al1s,
    const float* __restrict__ al1d, const float* __restrict__ b1,
    const int* __restrict__ rowptr, const int* __restrict__ cnt,
    const int* __restrict__ esrc, unsigned short* __restrict__ h1b) {
    __shared__ int s_src[4][64];
    __shared__ float s_alpha[4][64 * 8];
    int wv = threadIdx.x >> 6;
    int lane = threadIdx.x & 63;
    int n = blockIdx.x * 4 + wv;          // grid exactly covers 50000 = 12500*4
    int start = rowptr[n];
    int deg = cnt[n];
    int dcap = deg < 64 ? deg : 64;
    for (int j = lane; j < dcap; j += 64) s_src[wv][j] = esrc[start + j];
    // pass 1: online softmax stats, 8 edges x 8 heads
    int h = lane & 7, eg = lane >> 3;
    float ald = al1d[n * NH + h];
    float m = -1e30f, den = 0.f;
    for (int j = eg; j < dcap; j += 8) {
        int s = s_src[wv][j];
        float v = al1s[s * NH + h] + ald;
        v = v > 0.f ? v : NEG * v;
        if (v > m) { den = den * __expf(m - v) + 1.f; m = v; }
        else den += __expf(v - m);
    }
    for (int j = 64 + eg; j < deg; j += 8) {      // rare tail
        int s = esrc[start + j];
        float v = al1s[s * NH + h] + ald;
        v = v > 0.f ? v : NEG * v;
        if (v > m) { den = den * __expf(m - v) + 1.f; m = v; }
        else den += __expf(v - m);
    }
    for (int msk = 8; msk < 64; msk <<= 1) {
        float mo = __shfl_xor(m, msk), dn = __shfl_xor(den, msk);
        float nm = fmaxf(m, mo);
        den = den * __expf(m - nm) + dn * __expf(mo - nm);
        m = nm;
    }
    float rden1 = 1.f / den;
    // pass 1.5: alphas into LDS
    for (int j = eg; j < dcap; j += 8) {
        int s = s_src[wv][j];
        float v = al1s[s * NH + h] + ald;
        v = v > 0.f ? v : NEG * v;
        s_alpha[wv][j * 8 + h] = __expf(v - m) * rden1;
    }
    // pass 2: pure alpha*gather-fma, 4 gathers in flight per half-wave
    int eh = lane >> 5;
    int l5 = lane & 31;
    int h2 = l5 >> 2;
    float m2 = __shfl(m, h2);
    float rd2 = __shfl(rden1, h2);
    float ald2 = al1d[n * NH + h2];
    const int cb = l5 << 3;
    float acc[8] = {0.f, 0.f, 0.f, 0.f, 0.f, 0.f, 0.f, 0.f};
    for (int j0 = 0; j0 < dcap; j0 += 8) {
        const unsigned short* p[4];
        float a[4];
#pragma unroll
        for (int k = 0; k < 4; ++k) {
            int e = j0 + eh + 2 * k;
            bool act = e < dcap;
            int ee = act ? e : 0;
            int s = s_src[wv][ee];
            a[k] = act ? s_alpha[wv][ee * 8 + h2] : 0.f;
            p[k] = xp1b + (size_t)s * D1 + cb;
        }
#pragma unroll
        for (int k = 0; k < 4; ++k) {
            u16x8 xv = *(const u16x8*)p[k];
#pragma unroll
            for (int c = 0; c < 8; ++c) acc[c] = fmaf(a[k], bf2f(xv[c]), acc[c]);
        }
    }
    for (int j = 64 + eh; j < deg; j += 2) {      // rare tail
        int s = esrc[start + j];
        float v = al1s[s * NH + h2] + ald2;
        v = v > 0.f ? v : NEG * v;
        float al = __expf(v - m2) * rd2;
        u16x8 xv = *(const u16x8*)(xp1b + (size_t)s * D1 + cb);
#pragma unroll
        for (int c = 0; c < 8; ++c) acc[c] = fmaf(al, bf2f(xv[c]), acc[c]);
    }
#pragma unroll
    for (int c = 0; c < 8; ++c) acc[c] += __shfl_xor(acc[c], 32);
    if (eh == 0) {
        u16x8 pk;
#pragma unroll
        for (int c = 0; c < 8; ++c) {
            float av = acc[c] + b1[cb + c];
            av = av > 0.f ? av : expm1f(av);   // ELU fused
            pk[c] = f2bf(av);
        }
        *(u16x8*)(h1b + (size_t)n * D1 + cb) = pk;
    }
}

// ---------------- GEMM2 (bf16 h1 in) + al2 epilogue ---------------------------
__global__ __launch_bounds__(256) void k_gemm2(
    const unsigned short* __restrict__ h1b, const float* __restrict__ W2,
    const float* __restrict__ a2s, const float* __restrict__ a2d,
    float* __restrict__ xp2, float* __restrict__ al2s, float* __restrict__ al2d) {
    __shared__ float w2s[D1 * NCLS];
    for (int i = threadIdx.x; i < D1 * NCLS; i += 256) w2s[i] = W2[i];
    __syncthreads();
    int n = blockIdx.x * 256 + threadIdx.x;
    if (n >= N_NODES) return;
    float4 acc[4];
#pragma unroll
    for (int q = 0; q < 4; ++q) acc[q] = make_float4(0.f, 0.f, 0.f, 0.f);
    const unsigned short* hr = h1b + (size_t)n * D1;
    for (int k0 = 0; k0 < D1; k0 += 8) {
        u16x8 hv = *(const u16x8*)(hr + k0);
#pragma unroll
        for (int j = 0; j < 8; ++j) {
            float hx = bf2f(hv[j]);
#pragma unroll
            for (int q = 0; q < 4; ++q) {
                float4 w = *(const float4*)(&w2s[(k0 + j) * NCLS + q * 4]);
                acc[q].x = fmaf(hx, w.x, acc[q].x);
                acc[q].y = fmaf(hx, w.y, acc[q].y);
                acc[q].z = fmaf(hx, w.z, acc[q].z);
                acc[q].w = fmaf(hx, w.w, acc[q].w);
            }
        }
    }
    float ss = 0.f, dd = 0.f;
#pragma unroll
    for (int q = 0; q < 4; ++q) {
        *(float4*)(xp2 + (size_t)n * NCLS + q * 4) = acc[q];
        float4 s4 = *(const float4*)(a2s + q * 4);
        float4 d4 = *(const float4*)(a2d + q * 4);
        ss += acc[q].x * s4.x + acc[q].y * s4.y + acc[q].z * s4.z + acc[q].w * s4.w;
        dd += acc[q].x * d4.x + acc[q].y * d4.y + acc[q].z * d4.z + acc[q].w * d4.w;
    }
    al2s[n] = ss;
    al2d[n] = dd;
}

// ---------------- attention layer 2 (wave per dst node) -----------------------
__global__ __launch_bounds__(256) void k_att2(
    const float* __restrict__ xp2, const float* __restrict__ al2s,
    const float* __restrict__ al2d, const float* __restrict__ b2,
    const int* __restrict__ rowptr, const int* __restrict__ cnt,
    const int* __restrict__ esrc, float* __restrict__ out2) {
    int wave = threadIdx.x >> 6;
    int lane = threadIdx.x & 63;
    int n = blockIdx.x * 4 + wave;
    int start = rowptr[n];
    int deg = cnt[n];
    float ald = al2d[n];
    float m = -1e30f, den = 0.f;
    for (int j = lane; j < deg; j += 64) {
        float v = al2s[esrc[start + j]] + ald;
        v = v > 0.f ? v : NEG * v;
        if (v > m) { den = den * __expf(m - v) + 1.f; m = v; }
        else den += __expf(v - m);
    }
    for (int msk = 1; msk < 64; msk <<= 1) {
        float mo = __shfl_xor(m, msk), dn = __shfl_xor(den, msk);
        float nm = fmaxf(m, mo);
        den = den * __expf(m - nm) + dn * __expf(mo - nm);
        m = nm;
    }
    float rden = 1.f / den;
    int c = lane & 15;
    int eg = lane >> 4;                   // 4 edges x 16 channels
    float acc = 0.f;
    for (int j = eg; j < deg; j += 4) {
        int s = esrc[start + j];
        float v = al2s[s] + ald;
        v = v > 0.f ? v : NEG * v;
        acc += __expf(v - m) * rden * xp2[(size_t)s * NCLS + c];
    }
    acc += __shfl_xor(acc, 16);
    acc += __shfl_xor(acc, 32);
    if (lane < 16) out2[(size_t)n * NCLS + lane] = acc + b2[lane];
}

// ---------------- pooling (LDS pre-aggregation, sorted batch) -----------------
__global__ __launch_bounds__(256) void k_pool(
    const float* __restrict__ out2, const int* __restrict__ batch,
    float* __restrict__ poolS, float* __restrict__ poolC) {
    __shared__ float sacc[NGRP * NCLS];
    __shared__ float scnt[NGRP];
    for (int i = threadIdx.x; i < NGRP * NCLS; i += 256) sacc[i] = 0.f;
    if (threadIdx.x < NGRP) scnt[threadIdx.x] = 0.f;
    __syncthreads();
    int n = blockIdx.x * 256 + threadIdx.x;
    if (n < N_NODES) {
        int g = batch[n];
        atomicAdd(&scnt[g], 1.f);
#pragma unroll
        for (int cc = 0; cc < NCLS; ++cc)
            atomicAdd(&sacc[g * NCLS + cc], out2[(size_t)n * NCLS + cc]);
    }
    __syncthreads();
    for (int i = threadIdx.x; i < NGRP * NCLS; i += 256)
        if (sacc[i] != 0.f) atomicAdd(&poolS[i], sacc[i]);
    if (threadIdx.x < NGRP && scnt[threadIdx.x] != 0.f)
        atomicAdd(&poolC[threadIdx.x], scnt[threadIdx.x]);
}

__global__ void k_final(const float* __restrict__ poolS,
                        const float* __restrict__ poolC, float* __restrict__ out) {
    int g = threadIdx.x;
    if (g >= NGRP) return;
    float inv = 1.f / fmaxf(poolC[g], 1.f);
    float v[NCLS];
    float m = -1e30f;
#pragma unroll
    for (int c = 0; c < NCLS; ++c) {
        v[c] = poolS[g * NCLS + c] * inv;
        m = fmaxf(m, v[c]);
    }
    float s = 0.f;
#pragma unroll
    for (int c = 0; c < NCLS; ++c) s += expf(v[c] - m);
    float lse = m + logf(s);
#pragma unroll
    for (int c = 0; c < NCLS; ++c) out[g * NCLS + c] = v[c] - lse;
}

extern "C" void kernel_launch(void* const* d_in, const int* in_sizes, int n_in,
                              void* d_out, int out_size, void* d_ws, size_t ws_size,
                              hipStream_t stream) {
    const float* x    = (const float*)d_in[0];
    const int*   ei   = (const int*)d_in[1];
    const int*   batch = (const int*)d_in[2];
    const float* W1   = (const float*)d_in[3];
    const float* a1s  = (const float*)d_in[4];
    const float* a1d  = (const float*)d_in[5];
    const float* b1   = (const float*)d_in[6];
    const float* W2   = (const float*)d_in[7];
    const float* a2s  = (const float*)d_in[8];
    const float* a2d  = (const float*)d_in[9];
    const float* b2   = (const float*)d_in[10];
    float* out = (float*)d_out;

    float* f = (float*)d_ws;
    float* al1s_ = f;  f += (size_t)N_NODES * NH;
    float* al1d_ = f;  f += (size_t)N_NODES * NH;
    float* xp2   = f;  f += (size_t)N_NODES * NCLS;
    float* al2s_ = f;  f += N_NODES;
    float* al2d_ = f;  f += N_NODES;
    float* out2  = f;  f += (size_t)N_NODES * NCLS;
    float* poolS = f;  f += NGRP * NCLS;
    float* poolC = f;  f += NGRP;
    unsigned short* xp1b = (unsigned short*)f;
    unsigned short* h1b  = xp1b + (size_t)N_NODES * D1;
    unsigned short* w1t  = h1b + (size_t)N_NODES * D1;
    int* cnt    = (int*)(w1t + FDIM * D1);
    int* rowptr = cnt + N_NODES;
    int* cursor = rowptr + N_NODES;
    int* esrc   = cursor + N_NODES;
    int* bsums  = esrc + E_TOT;

    const int NB_N = (N_NODES + 255) / 256;   // 196

    k_init<<<NB_N, 256, 0, stream>>>(W1, w1t, cnt, poolS, poolC);
    k_gemm1m<<<(N_NODES + 63) / 64, 256, 0, stream>>>(x, w1t, a1s, a1d, xp1b, al1s_, al1d_);
    k_hist<<<(N_EDGES + 255) / 256, 256, 0, stream>>>(ei, cnt);
    k_scan1<<<NB_N, 256, 0, stream>>>(cnt, rowptr, bsums);
    k_scan2<<<1, 256, 0, stream>>>(bsums, NB_N);
    k_scan3<<<NB_N, 256, 0, stream>>>(rowptr, bsums, cursor);
    k_scatter<<<(E_TOT + 255) / 256, 256, 0, stream>>>(ei, cursor, esrc);
    k_att1<<<N_NODES / 4, 256, 0, stream>>>(xp1b, al1s_, al1d_, b1, rowptr, cnt, esrc, h1b);
    k_gemm2<<<NB_N, 256, 0, stream>>>(h1b, W2, a2s, a2d, xp2, al2s_, al2d_);
    k_att2<<<N_NODES / 4, 256, 0, stream>>>(xp2, al2s_, al2d_, b2, rowptr, cnt, esrc, out2);
    k_pool<<<NB_N, 256, 0, stream>>>(out2, batch, poolS, poolC);
    k_final<<<1, 64, 0, stream>>>(poolS, poolC, out);
}